// Round 11
// baseline (322.757 us; speedup 1.0000x reference)
//
#include <hip/hip_runtime.h>
#include <math.h>

#define BATCH   4096
#define FEAT    64
#define EMB     32
#define MODELS  512
#define SEQ     128
#define KDIM    (FEAT * EMB)   // 2048

#define SQRT_MODELS 22.62741699796952f
#define LN10000     9.210340371976184f

typedef __attribute__((ext_vector_type(4))) float        f32x4;
typedef __attribute__((ext_vector_type(8))) short        bf16x8;
typedef __attribute__((ext_vector_type(4))) unsigned int u32x4;

// ws layout: Wt | pe | x | Abf   (x slot unused by full path; kept for layout stability)
#define WT_BYTES  ((size_t)MODELS * KDIM * 2)          // 2 MB   bf16 W^T, pre-scaled
#define PE_BYTES  ((size_t)SEQ * MODELS * 4)           // 256 KB pe + bias
#define X_BYTES   ((size_t)BATCH * MODELS * 4)         // 8 MB
#define ABF_BYTES ((size_t)BATCH * KDIM * 2)           // 16 MB  dense bf16 A
#define WS_MID    (WT_BYTES + PE_BYTES + X_BYTES)
#define WS_FULL   (WT_BYTES + PE_BYTES + X_BYTES + ABF_BYTES)

__device__ inline unsigned short bf16_rne(float f) {
    unsigned int b = __builtin_bit_cast(unsigned int, f);
    return (unsigned short)((b + 0x7FFFu + ((b >> 16) & 1u)) >> 16);
}

#define CVT_PK4(pk, v0, v1)                                                     \
    {                                                                           \
        unsigned int q0, q1, q2, q3;                                            \
        asm("v_cvt_pk_bf16_f32 %0, %1, %2" : "=v"(q0) : "v"(v0.x), "v"(v0.y));  \
        asm("v_cvt_pk_bf16_f32 %0, %1, %2" : "=v"(q1) : "v"(v0.z), "v"(v0.w));  \
        asm("v_cvt_pk_bf16_f32 %0, %1, %2" : "=v"(q2) : "v"(v1.x), "v"(v1.y));  \
        asm("v_cvt_pk_bf16_f32 %0, %1, %2" : "=v"(q3) : "v"(v1.z), "v"(v1.w));  \
        pk = (u32x4){q0, q1, q2, q3};                                           \
    }

// ---------------- prep_all: Wt transpose | pe table | dense gather (proven R7) ----------------
__global__ __launch_bounds__(256)
void prep_all(const int* __restrict__ tokens, const float* __restrict__ emb,
              const float* __restrict__ W, const float* __restrict__ bias,
              unsigned short* __restrict__ Wt, float* __restrict__ pe,
              unsigned short* __restrict__ Abf) {
    const int bx  = blockIdx.x;
    const int tid = threadIdx.x;

    if (bx < 1024) {
        __shared__ float t[32][33];
        const int k0 = (bx & 63) * 32;
        const int n0 = (bx >> 6) * 32;
        const int tx = tid & 31;
        const int ty = tid >> 5;
        #pragma unroll
        for (int i = 0; i < 4; ++i)
            t[ty + i * 8][tx] = W[(size_t)(k0 + ty + i * 8) * MODELS + n0 + tx] * SQRT_MODELS;
        __syncthreads();
        #pragma unroll
        for (int i = 0; i < 4; ++i)
            Wt[(size_t)(n0 + ty + i * 8) * KDIM + k0 + tx] = bf16_rne(t[tx][ty + i * 8]);
    } else if (bx < 1280) {
        const int idx = (bx - 1024) * 256 + tid;
        const int s = idx >> 9;
        const int m = idx & (MODELS - 1);
        const float rate = expf(-LN10000 * (float)(2 * (m >> 1)) * (1.0f / 512.0f));
        const float ang  = (float)s * rate;
        pe[idx] = ((m & 1) ? cosf(ang) : sinf(ang)) + bias[m];
    } else {
        const int g    = (bx - 1280) * 256 + tid;     // 0 .. 1M-1
        const int fr   = g >> 2;
        const int part = g & 3;
        const int tok  = tokens[fr];
        const float* src = emb + (size_t)tok * EMB + part * 8;
        const f32x4 v0 = *(const f32x4*)src;
        const f32x4 v1 = *(const f32x4*)(src + 4);
        u32x4 pk;
        CVT_PK4(pk, v0, v1);
        *(u32x4*)(Abf + (size_t)g * 8) = pk;
    }
}

// ---------------- fused: Abf-fed MFMA (R6-verified inner) + R5-verified LDS/store ----------------
// grid 256 x 512 thr (1 block/CU, 8 waves). Phase A: wave w computes x[16][w*64..+64]
// reading A rows from dense Abf (R6 gemm_tilegroup pattern, verified) and Wt cols.
// Phase B: R5's exact store mapping (verified): 16 rows x 128 seq x 512 cols, NT stores.
#define XS_STRIDE 516   // floats; R5-verified layout

__global__ __launch_bounds__(512)
void gemm_bcast_abf(const unsigned short* __restrict__ Abf,
                    const unsigned short* __restrict__ Wt,
                    const float* __restrict__ pe,
                    float* __restrict__ out) {
    __shared__ float xs[16 * XS_STRIDE];   // 33 KB

    const int tid  = threadIdx.x;
    const int wave = tid >> 6;             // 0..7
    const int lane = tid & 63;
    const int ln   = lane & 15;            // A row idx / D col idx
    const int kg   = lane >> 4;            // k-group of 8

    const int m0     = blockIdx.x * 16;
    const int n_base = wave * 64;

    // ---- Phase A: GEMM 16 x 64 per wave, K = 2048 (R6-verified inner loop) ----
    const unsigned short* ap = Abf + (size_t)(m0 + ln) * KDIM + kg * 8;
    const unsigned short* bp = Wt  + (size_t)(n_base + ln) * KDIM + kg * 8;

    f32x4 acc[4] = {f32x4{0,0,0,0}, f32x4{0,0,0,0}, f32x4{0,0,0,0}, f32x4{0,0,0,0}};

    #pragma unroll 4
    for (int k = 0; k < KDIM; k += 32) {
        const bf16x8 a = *(const bf16x8*)(ap + k);
        #pragma unroll
        for (int nf = 0; nf < 4; ++nf) {
            const bf16x8 b = *(const bf16x8*)(bp + (size_t)nf * 16 * KDIM + k);
            acc[nf] = __builtin_amdgcn_mfma_f32_16x16x32_bf16(a, b, acc[nf], 0, 0, 0);
        }
    }

    // D mapping (verified): col = lane&15, row = (lane>>4)*4 + reg  (R5 exact line)
    #pragma unroll
    for (int nf = 0; nf < 4; ++nf)
        #pragma unroll
        for (int q = 0; q < 4; ++q)
            xs[(kg * 4 + q) * XS_STRIDE + n_base + nf * 16 + ln] = acc[nf][q];

    __syncthreads();

    // ---- Phase B: out[m0+r][s][:] = x[r][:] + pe[s][:]  (R5 exact mapping) ----
    const int r = tid >> 5;                // 0..15
    const int c = (tid & 31) * 4;          // 0..124 (floats)

    f32x4 xv[4];
    #pragma unroll
    for (int p = 0; p < 4; ++p)
        xv[p] = *(const f32x4*)&xs[r * XS_STRIDE + p * 128 + c];

    float* ob = out + (size_t)(m0 + r) * SEQ * MODELS;
    const float* peb = pe;
    #pragma unroll 2
    for (int s = 0; s < SEQ; ++s) {
        const size_t so = (size_t)s * MODELS;
        #pragma unroll
        for (int p = 0; p < 4; ++p) {
            const f32x4 pv = *(const f32x4*)(peb + so + p * 128 + c);
            __builtin_nontemporal_store(xv[p] + pv, (f32x4*)(ob + so + p * 128 + c));
        }
    }
}

// ---------------- mid-path (proven R2): gather-direct MFMA + separate bcast ----------------
__global__ __launch_bounds__(256)
void gemm_mfma(const int* __restrict__ tokens, const float* __restrict__ emb,
               const unsigned short* __restrict__ Wt, float* __restrict__ x) {
    const int tid  = threadIdx.x;
    const int wave = tid >> 6;
    const int lane = tid & 63;
    const int ln   = lane & 15;
    const int kg   = lane >> 4;
    const int m_base = blockIdx.y * 16;
    const int n_base = blockIdx.x * 256 + wave * 64;
    const int* trow = tokens + (size_t)(m_base + ln) * FEAT;
    const unsigned short* bptr[4];
    #pragma unroll
    for (int nf = 0; nf < 4; ++nf)
        bptr[nf] = Wt + (size_t)(n_base + nf * 16 + ln) * KDIM + kg * 8;
    f32x4 acc[4] = {f32x4{0,0,0,0}, f32x4{0,0,0,0}, f32x4{0,0,0,0}, f32x4{0,0,0,0}};
    for (int f4 = 0; f4 < FEAT; f4 += 4) {
        const int4 tok4 = *(const int4*)(trow + f4);
        const int toks[4] = {tok4.x, tok4.y, tok4.z, tok4.w};
        #pragma unroll
        for (int j = 0; j < 4; ++j) {
            const int f = f4 + j;
            const float* ea = emb + (size_t)toks[j] * EMB + kg * 8;
            const f32x4 a0 = *(const f32x4*)ea;
            const f32x4 a1 = *(const f32x4*)(ea + 4);
            u32x4 pk;
            CVT_PK4(pk, a0, a1);
            const bf16x8 afrag = __builtin_bit_cast(bf16x8, pk);
            #pragma unroll
            for (int nf = 0; nf < 4; ++nf) {
                const bf16x8 bfrag = *(const bf16x8*)(bptr[nf] + (size_t)f * EMB);
                acc[nf] = __builtin_amdgcn_mfma_f32_16x16x32_bf16(afrag, bfrag, acc[nf], 0, 0, 0);
            }
        }
    }
    #pragma unroll
    for (int nf = 0; nf < 4; ++nf)
        #pragma unroll
        for (int q = 0; q < 4; ++q)
            x[(size_t)(m_base + kg * 4 + q) * MODELS + n_base + nf * 16 + ln] = acc[nf][q];
}

__global__ __launch_bounds__(256)
void bcast_pe(const float* __restrict__ x, const float* __restrict__ pe,
              float* __restrict__ out) {
    const int tid = threadIdx.x;
    const int m4  = tid & 127;
    const int b   = blockIdx.x * 2 + (tid >> 7);
    const f32x4 xv = *(const f32x4*)(x + (size_t)b * MODELS + m4 * 4);
    const f32x4* pev = (const f32x4*)pe;
    float* ob = out + (size_t)b * SEQ * MODELS + m4 * 4;
    #pragma unroll 8
    for (int s = 0; s < SEQ; ++s) {
        const f32x4 p = pev[s * 128 + m4];
        __builtin_nontemporal_store(xv + p, (f32x4*)(ob + (size_t)s * MODELS));
    }
}

__global__ __launch_bounds__(256)
void prep_wt(const float* __restrict__ W, unsigned short* __restrict__ Wt) {
    __shared__ float t[32][33];
    const int k0 = blockIdx.x * 32;
    const int n0 = blockIdx.y * 32;
    const int tx = threadIdx.x;
    const int ty = threadIdx.y;
    #pragma unroll
    for (int i = 0; i < 4; ++i)
        t[ty + i * 8][tx] = W[(size_t)(k0 + ty + i * 8) * MODELS + n0 + tx] * SQRT_MODELS;
    __syncthreads();
    #pragma unroll
    for (int i = 0; i < 4; ++i)
        Wt[(size_t)(n0 + ty + i * 8) * KDIM + k0 + tx] = bf16_rne(t[tx][ty + i * 8]);
}

__global__ __launch_bounds__(256)
void prep_pe(const float* __restrict__ bias, float* __restrict__ pe) {
    const int idx = blockIdx.x * 256 + threadIdx.x;
    const int s = idx >> 9;
    const int m = idx & (MODELS - 1);
    const float rate = expf(-LN10000 * (float)(2 * (m >> 1)) * (1.0f / 512.0f));
    const float ang  = (float)s * rate;
    pe[idx] = ((m & 1) ? cosf(ang) : sinf(ang)) + bias[m];
}

// ---------------- last-resort fallback: verified round-1 fused kernel ----------------
#define BM 64
#define BN 64
#define BK 32
__global__ __launch_bounds__(256, 2)
void fused_emb_gemm_pe(const int* __restrict__ tokens, const float* __restrict__ emb,
                       const float* __restrict__ W, const float* __restrict__ bias,
                       float* __restrict__ out) {
    __shared__ float As[BK][BM];
    __shared__ float Bs[BK][BN];
    __shared__ float peS[SEQ][BN];
    const int tid  = threadIdx.x;
    const int bn   = blockIdx.x * BN;
    const int brow = blockIdx.y * BM;
    for (int idx = tid; idx < SEQ * BN; idx += 256) {
        const int s  = idx >> 6;
        const int ml = idx & 63;
        const int m  = bn + ml;
        const float rate = expf(-LN10000 * (float)(2 * (m >> 1)) * (1.0f / 512.0f));
        const float ang  = (float)s * rate;
        peS[s][ml] = (m & 1) ? cosf(ang) : sinf(ang);
    }
    float acc[4][4] = {};
    const int tx = tid & 15;
    const int ty = tid >> 4;
    const int lr = tid >> 2;
    const int lj = tid & 3;
    const int bk = tid >> 4;
    const int bc = (tid & 15) * 4;
    for (int kt = 0; kt < FEAT; ++kt) {
        __syncthreads();
        {
            const int tok = tokens[(brow + lr) * FEAT + kt];
            const float* erow = emb + (size_t)tok * EMB + lj * 8;
            const float4 a0 = *(const float4*)(erow);
            const float4 a1 = *(const float4*)(erow + 4);
            const int k0 = lj * 8;
            As[k0 + 0][lr] = a0.x * SQRT_MODELS; As[k0 + 1][lr] = a0.y * SQRT_MODELS;
            As[k0 + 2][lr] = a0.z * SQRT_MODELS; As[k0 + 3][lr] = a0.w * SQRT_MODELS;
            As[k0 + 4][lr] = a1.x * SQRT_MODELS; As[k0 + 5][lr] = a1.y * SQRT_MODELS;
            As[k0 + 6][lr] = a1.z * SQRT_MODELS; As[k0 + 7][lr] = a1.w * SQRT_MODELS;
        }
        {
            const float* w0 = W + (size_t)(kt * 32 + bk) * MODELS + bn + bc;
            const float* w1 = W + (size_t)(kt * 32 + bk + 16) * MODELS + bn + bc;
            *(float4*)&Bs[bk][bc]      = *(const float4*)w0;
            *(float4*)&Bs[bk + 16][bc] = *(const float4*)w1;
        }
        __syncthreads();
        #pragma unroll
        for (int k = 0; k < BK; ++k) {
            const float4 a = *(const float4*)&As[k][ty * 4];
            const float4 b = *(const float4*)&Bs[k][tx * 4];
            acc[0][0] += a.x * b.x; acc[0][1] += a.x * b.y; acc[0][2] += a.x * b.z; acc[0][3] += a.x * b.w;
            acc[1][0] += a.y * b.x; acc[1][1] += a.y * b.y; acc[1][2] += a.y * b.z; acc[1][3] += a.y * b.w;
            acc[2][0] += a.z * b.x; acc[2][1] += a.z * b.y; acc[2][2] += a.z * b.z; acc[2][3] += a.z * b.w;
            acc[3][0] += a.w * b.x; acc[3][1] += a.w * b.y; acc[3][2] += a.w * b.z; acc[3][3] += a.w * b.w;
        }
    }
    {
        const float4 bv = *(const float4*)(bias + bn + tx * 4);
        #pragma unroll
        for (int i = 0; i < 4; ++i) {
            acc[i][0] += bv.x; acc[i][1] += bv.y; acc[i][2] += bv.z; acc[i][3] += bv.w;
        }
    }
    size_t rowbase[4];
    #pragma unroll
    for (int i = 0; i < 4; ++i)
        rowbase[i] = ((size_t)(brow + ty * 4 + i) * SEQ) * MODELS + bn + tx * 4;
    #pragma unroll 4
    for (int s = 0; s < SEQ; ++s) {
        const float4 pv = *(const float4*)&peS[s][tx * 4];
        const size_t soff = (size_t)s * MODELS;
        #pragma unroll
        for (int i = 0; i < 4; ++i) {
            float4 o;
            o.x = acc[i][0] + pv.x; o.y = acc[i][1] + pv.y;
            o.z = acc[i][2] + pv.z; o.w = acc[i][3] + pv.w;
            *(float4*)(out + rowbase[i] + soff) = o;
        }
    }
}

extern "C" void kernel_launch(void* const* d_in, const int* in_sizes, int n_in,
                              void* d_out, int out_size, void* d_ws, size_t ws_size,
                              hipStream_t stream) {
    const int*   tokens = (const int*)d_in[0];
    const float* emb    = (const float*)d_in[1];
    const float* W      = (const float*)d_in[2];
    const float* bias   = (const float*)d_in[3];
    float*       out    = (float*)d_out;

    if (ws_size >= WS_FULL) {
        char* w = (char*)d_ws;
        unsigned short* Wt  = (unsigned short*)w;
        float*          pe  = (float*)(w + WT_BYTES);
        unsigned short* Abf = (unsigned short*)(w + WT_BYTES + PE_BYTES + X_BYTES);

        prep_all<<<dim3(1024 + 256 + 4096), dim3(256), 0, stream>>>(
            tokens, emb, W, bias, Wt, pe, Abf);
        gemm_bcast_abf<<<dim3(BATCH / 16), dim3(512), 0, stream>>>(Abf, Wt, pe, out);
    } else if (ws_size >= WS_MID) {
        char* w = (char*)d_ws;
        unsigned short* Wt = (unsigned short*)w;
        float* pe = (float*)(w + WT_BYTES);
        float* x  = (float*)(w + WT_BYTES + PE_BYTES);

        prep_wt<<<dim3(KDIM / 32, MODELS / 32), dim3(32, 8), 0, stream>>>(W, Wt);
        prep_pe<<<dim3(SEQ * MODELS / 256), dim3(256), 0, stream>>>(bias, pe);
        gemm_mfma<<<dim3(MODELS / 256, BATCH / 16), dim3(256), 0, stream>>>(tokens, emb, Wt, x);
        bcast_pe<<<dim3(BATCH / 2), dim3(256), 0, stream>>>(x, pe, out);
    } else {
        fused_emb_gemm_pe<<<dim3(MODELS / BN, BATCH / BM), dim3(256), 0, stream>>>(
            tokens, emb, W, bias, out);
    }
}

// Round 12
// 268.953 us; speedup vs baseline: 1.2001x; 1.2001x over previous
//
#include <hip/hip_runtime.h>
#include <math.h>

#define BATCH   4096
#define FEAT    64
#define EMB     32
#define MODELS  512
#define SEQ     128
#define KDIM    (FEAT * EMB)   // 2048

#define SQRT_MODELS 22.62741699796952f
#define LN10000     9.210340371976184f

typedef __attribute__((ext_vector_type(4))) float        f32x4;
typedef __attribute__((ext_vector_type(8))) short        bf16x8;
typedef __attribute__((ext_vector_type(4))) unsigned int u32x4;

// ws layout: Wt | pe | x | Abf
#define WT_BYTES  ((size_t)MODELS * KDIM * 2)          // 2 MB   bf16 W^T, pre-scaled
#define PE_BYTES  ((size_t)SEQ * MODELS * 4)           // 256 KB pe + bias
#define X_BYTES   ((size_t)BATCH * MODELS * 4)         // 8 MB
#define ABF_BYTES ((size_t)BATCH * KDIM * 2)           // 16 MB  dense bf16 A
#define WS_MID    (WT_BYTES + PE_BYTES + X_BYTES)
#define WS_FULL   (WT_BYTES + PE_BYTES + X_BYTES + ABF_BYTES)

__device__ inline unsigned short bf16_rne(float f) {
    unsigned int b = __builtin_bit_cast(unsigned int, f);
    return (unsigned short)((b + 0x7FFFu + ((b >> 16) & 1u)) >> 16);
}

#define CVT_PK4(pk, v0, v1)                                                     \
    {                                                                           \
        unsigned int q0, q1, q2, q3;                                            \
        asm("v_cvt_pk_bf16_f32 %0, %1, %2" : "=v"(q0) : "v"(v0.x), "v"(v0.y));  \
        asm("v_cvt_pk_bf16_f32 %0, %1, %2" : "=v"(q1) : "v"(v0.z), "v"(v0.w));  \
        asm("v_cvt_pk_bf16_f32 %0, %1, %2" : "=v"(q2) : "v"(v1.x), "v"(v1.y));  \
        asm("v_cvt_pk_bf16_f32 %0, %1, %2" : "=v"(q3) : "v"(v1.z), "v"(v1.w));  \
        pk = (u32x4){q0, q1, q2, q3};                                           \
    }

// ---------------- prep_all: Wt transpose | pe table | dense gather (proven R7) ----------------
__global__ __launch_bounds__(256)
void prep_all(const int* __restrict__ tokens, const float* __restrict__ emb,
              const float* __restrict__ W, const float* __restrict__ bias,
              unsigned short* __restrict__ Wt, float* __restrict__ pe,
              unsigned short* __restrict__ Abf) {
    const int bx  = blockIdx.x;
    const int tid = threadIdx.x;

    if (bx < 1024) {
        __shared__ float t[32][33];
        const int k0 = (bx & 63) * 32;
        const int n0 = (bx >> 6) * 32;
        const int tx = tid & 31;
        const int ty = tid >> 5;
        #pragma unroll
        for (int i = 0; i < 4; ++i)
            t[ty + i * 8][tx] = W[(size_t)(k0 + ty + i * 8) * MODELS + n0 + tx] * SQRT_MODELS;
        __syncthreads();
        #pragma unroll
        for (int i = 0; i < 4; ++i)
            Wt[(size_t)(n0 + ty + i * 8) * KDIM + k0 + tx] = bf16_rne(t[tx][ty + i * 8]);
    } else if (bx < 1280) {
        const int idx = (bx - 1024) * 256 + tid;
        const int s = idx >> 9;
        const int m = idx & (MODELS - 1);
        const float rate = expf(-LN10000 * (float)(2 * (m >> 1)) * (1.0f / 512.0f));
        const float ang  = (float)s * rate;
        pe[idx] = ((m & 1) ? cosf(ang) : sinf(ang)) + bias[m];
    } else {
        const int g    = (bx - 1280) * 256 + tid;     // 0 .. 1M-1
        const int fr   = g >> 2;
        const int part = g & 3;
        const int tok  = tokens[fr];
        const float* src = emb + (size_t)tok * EMB + part * 8;
        const f32x4 v0 = *(const f32x4*)src;
        const f32x4 v1 = *(const f32x4*)(src + 4);
        u32x4 pk;
        CVT_PK4(pk, v0, v1);
        *(u32x4*)(Abf + (size_t)g * 8) = pk;
    }
}

// ---------------- GEMM: x = Abf @ Wt^T  (R7-verified; unroll 4 -> 8, no VGPR cap) ----------------
__global__ __launch_bounds__(256)
void gemm_dense(const unsigned short* __restrict__ Abf,
                const unsigned short* __restrict__ Wt,
                float* __restrict__ x) {
    const int tid  = threadIdx.x;
    const int lane = tid & 63;
    const int wave = tid >> 6;
    const int ln   = lane & 15;
    const int kg   = lane >> 4;
    const int m0 = blockIdx.y * 64 + (wave >> 1) * 32;
    const int n0 = blockIdx.x * 64 + (wave & 1) * 32;

    const unsigned short* a0p = Abf + (size_t)(m0 + ln) * KDIM + kg * 8;
    const unsigned short* a1p = a0p + 16 * KDIM;
    const unsigned short* b0p = Wt + (size_t)(n0 + ln) * KDIM + kg * 8;
    const unsigned short* b1p = b0p + 16 * KDIM;

    f32x4 acc00 = {0,0,0,0}, acc01 = {0,0,0,0};
    f32x4 acc10 = {0,0,0,0}, acc11 = {0,0,0,0};

    #pragma unroll 8
    for (int k = 0; k < KDIM; k += 32) {
        const bf16x8 a0 = *(const bf16x8*)(a0p + k);
        const bf16x8 a1 = *(const bf16x8*)(a1p + k);
        const bf16x8 b0 = *(const bf16x8*)(b0p + k);
        const bf16x8 b1 = *(const bf16x8*)(b1p + k);
        acc00 = __builtin_amdgcn_mfma_f32_16x16x32_bf16(a0, b0, acc00, 0, 0, 0);
        acc01 = __builtin_amdgcn_mfma_f32_16x16x32_bf16(a0, b1, acc01, 0, 0, 0);
        acc10 = __builtin_amdgcn_mfma_f32_16x16x32_bf16(a1, b0, acc10, 0, 0, 0);
        acc11 = __builtin_amdgcn_mfma_f32_16x16x32_bf16(a1, b1, acc11, 0, 0, 0);
    }
    // D mapping (verified): col = lane&15, row = (lane>>4)*4 + reg
    #pragma unroll
    for (int q = 0; q < 4; ++q) {
        const int r = kg * 4 + q;
        x[(size_t)(m0 + r)      * MODELS + n0 + ln]      = acc00[q];
        x[(size_t)(m0 + r)      * MODELS + n0 + 16 + ln] = acc01[q];
        x[(size_t)(m0 + 16 + r) * MODELS + n0 + ln]      = acc10[q];
        x[(size_t)(m0 + 16 + r) * MODELS + n0 + 16 + ln] = acc11[q];
    }
}

// ---------------- bcast: out[b][s][m] = x[b][m] + pe[s][m], NT stores (proven R7; unroll 16) ----------------
__global__ __launch_bounds__(256)
void bcast_pe(const float* __restrict__ x, const float* __restrict__ pe,
              float* __restrict__ out) {
    const int tid = threadIdx.x;
    const int m4  = tid & 127;
    const int b   = blockIdx.x * 2 + (tid >> 7);
    const f32x4 xv = *(const f32x4*)(x + (size_t)b * MODELS + m4 * 4);
    const f32x4* pev = (const f32x4*)pe;
    float* ob = out + (size_t)b * SEQ * MODELS + m4 * 4;
    #pragma unroll 16
    for (int s = 0; s < SEQ; ++s) {
        const f32x4 p = pev[s * 128 + m4];
        __builtin_nontemporal_store(xv + p, (f32x4*)(ob + (size_t)s * MODELS));
    }
}

// ---------------- mid-path (proven R2): gather-direct MFMA + separate bcast ----------------
__global__ __launch_bounds__(256)
void gemm_mfma(const int* __restrict__ tokens, const float* __restrict__ emb,
               const unsigned short* __restrict__ Wt, float* __restrict__ x) {
    const int tid  = threadIdx.x;
    const int wave = tid >> 6;
    const int lane = tid & 63;
    const int ln   = lane & 15;
    const int kg   = lane >> 4;
    const int m_base = blockIdx.y * 16;
    const int n_base = blockIdx.x * 256 + wave * 64;
    const int* trow = tokens + (size_t)(m_base + ln) * FEAT;
    const unsigned short* bptr[4];
    #pragma unroll
    for (int nf = 0; nf < 4; ++nf)
        bptr[nf] = Wt + (size_t)(n_base + nf * 16 + ln) * KDIM + kg * 8;
    f32x4 acc[4] = {f32x4{0,0,0,0}, f32x4{0,0,0,0}, f32x4{0,0,0,0}, f32x4{0,0,0,0}};
    for (int f4 = 0; f4 < FEAT; f4 += 4) {
        const int4 tok4 = *(const int4*)(trow + f4);
        const int toks[4] = {tok4.x, tok4.y, tok4.z, tok4.w};
        #pragma unroll
        for (int j = 0; j < 4; ++j) {
            const int f = f4 + j;
            const float* ea = emb + (size_t)toks[j] * EMB + kg * 8;
            const f32x4 a0 = *(const f32x4*)ea;
            const f32x4 a1 = *(const f32x4*)(ea + 4);
            u32x4 pk;
            CVT_PK4(pk, a0, a1);
            const bf16x8 afrag = __builtin_bit_cast(bf16x8, pk);
            #pragma unroll
            for (int nf = 0; nf < 4; ++nf) {
                const bf16x8 bfrag = *(const bf16x8*)(bptr[nf] + (size_t)f * EMB);
                acc[nf] = __builtin_amdgcn_mfma_f32_16x16x32_bf16(afrag, bfrag, acc[nf], 0, 0, 0);
            }
        }
    }
    #pragma unroll
    for (int nf = 0; nf < 4; ++nf)
        #pragma unroll
        for (int q = 0; q < 4; ++q)
            x[(size_t)(m_base + kg * 4 + q) * MODELS + n_base + nf * 16 + ln] = acc[nf][q];
}

__global__ __launch_bounds__(256)
void prep_wt(const float* __restrict__ W, unsigned short* __restrict__ Wt) {
    __shared__ float t[32][33];
    const int k0 = blockIdx.x * 32;
    const int n0 = blockIdx.y * 32;
    const int tx = threadIdx.x;
    const int ty = threadIdx.y;
    #pragma unroll
    for (int i = 0; i < 4; ++i)
        t[ty + i * 8][tx] = W[(size_t)(k0 + ty + i * 8) * MODELS + n0 + tx] * SQRT_MODELS;
    __syncthreads();
    #pragma unroll
    for (int i = 0; i < 4; ++i)
        Wt[(size_t)(n0 + ty + i * 8) * KDIM + k0 + tx] = bf16_rne(t[tx][ty + i * 8]);
}

__global__ __launch_bounds__(256)
void prep_pe(const float* __restrict__ bias, float* __restrict__ pe) {
    const int idx = blockIdx.x * 256 + threadIdx.x;
    const int s = idx >> 9;
    const int m = idx & (MODELS - 1);
    const float rate = expf(-LN10000 * (float)(2 * (m >> 1)) * (1.0f / 512.0f));
    const float ang  = (float)s * rate;
    pe[idx] = ((m & 1) ? cosf(ang) : sinf(ang)) + bias[m];
}

// ---------------- last-resort fallback: verified round-1 fused kernel ----------------
#define BM 64
#define BN 64
#define BK 32
__global__ __launch_bounds__(256, 2)
void fused_emb_gemm_pe(const int* __restrict__ tokens, const float* __restrict__ emb,
                       const float* __restrict__ W, const float* __restrict__ bias,
                       float* __restrict__ out) {
    __shared__ float As[BK][BM];
    __shared__ float Bs[BK][BN];
    __shared__ float peS[SEQ][BN];
    const int tid  = threadIdx.x;
    const int bn   = blockIdx.x * BN;
    const int brow = blockIdx.y * BM;
    for (int idx = tid; idx < SEQ * BN; idx += 256) {
        const int s  = idx >> 6;
        const int ml = idx & 63;
        const int m  = bn + ml;
        const float rate = expf(-LN10000 * (float)(2 * (m >> 1)) * (1.0f / 512.0f));
        const float ang  = (float)s * rate;
        peS[s][ml] = (m & 1) ? cosf(ang) : sinf(ang);
    }
    float acc[4][4] = {};
    const int tx = tid & 15;
    const int ty = tid >> 4;
    const int lr = tid >> 2;
    const int lj = tid & 3;
    const int bk = tid >> 4;
    const int bc = (tid & 15) * 4;
    for (int kt = 0; kt < FEAT; ++kt) {
        __syncthreads();
        {
            const int tok = tokens[(brow + lr) * FEAT + kt];
            const float* erow = emb + (size_t)tok * EMB + lj * 8;
            const float4 a0 = *(const float4*)(erow);
            const float4 a1 = *(const float4*)(erow + 4);
            const int k0 = lj * 8;
            As[k0 + 0][lr] = a0.x * SQRT_MODELS; As[k0 + 1][lr] = a0.y * SQRT_MODELS;
            As[k0 + 2][lr] = a0.z * SQRT_MODELS; As[k0 + 3][lr] = a0.w * SQRT_MODELS;
            As[k0 + 4][lr] = a1.x * SQRT_MODELS; As[k0 + 5][lr] = a1.y * SQRT_MODELS;
            As[k0 + 6][lr] = a1.z * SQRT_MODELS; As[k0 + 7][lr] = a1.w * SQRT_MODELS;
        }
        {
            const float* w0 = W + (size_t)(kt * 32 + bk) * MODELS + bn + bc;
            const float* w1 = W + (size_t)(kt * 32 + bk + 16) * MODELS + bn + bc;
            *(float4*)&Bs[bk][bc]      = *(const float4*)w0;
            *(float4*)&Bs[bk + 16][bc] = *(const float4*)w1;
        }
        __syncthreads();
        #pragma unroll
        for (int k = 0; k < BK; ++k) {
            const float4 a = *(const float4*)&As[k][ty * 4];
            const float4 b = *(const float4*)&Bs[k][tx * 4];
            acc[0][0] += a.x * b.x; acc[0][1] += a.x * b.y; acc[0][2] += a.x * b.z; acc[0][3] += a.x * b.w;
            acc[1][0] += a.y * b.x; acc[1][1] += a.y * b.y; acc[1][2] += a.y * b.z; acc[1][3] += a.y * b.w;
            acc[2][0] += a.z * b.x; acc[2][1] += a.z * b.y; acc[2][2] += a.z * b.z; acc[2][3] += a.z * b.w;
            acc[3][0] += a.w * b.x; acc[3][1] += a.w * b.y; acc[3][2] += a.w * b.z; acc[3][3] += a.w * b.w;
        }
    }
    {
        const float4 bv = *(const float4*)(bias + bn + tx * 4);
        #pragma unroll
        for (int i = 0; i < 4; ++i) {
            acc[i][0] += bv.x; acc[i][1] += bv.y; acc[i][2] += bv.z; acc[i][3] += bv.w;
        }
    }
    size_t rowbase[4];
    #pragma unroll
    for (int i = 0; i < 4; ++i)
        rowbase[i] = ((size_t)(brow + ty * 4 + i) * SEQ) * MODELS + bn + tx * 4;
    #pragma unroll 4
    for (int s = 0; s < SEQ; ++s) {
        const float4 pv = *(const float4*)&peS[s][tx * 4];
        const size_t soff = (size_t)s * MODELS;
        #pragma unroll
        for (int i = 0; i < 4; ++i) {
            float4 o;
            o.x = acc[i][0] + pv.x; o.y = acc[i][1] + pv.y;
            o.z = acc[i][2] + pv.z; o.w = acc[i][3] + pv.w;
            *(float4*)(out + rowbase[i] + soff) = o;
        }
    }
}

extern "C" void kernel_launch(void* const* d_in, const int* in_sizes, int n_in,
                              void* d_out, int out_size, void* d_ws, size_t ws_size,
                              hipStream_t stream) {
    const int*   tokens = (const int*)d_in[0];
    const float* emb    = (const float*)d_in[1];
    const float* W      = (const float*)d_in[2];
    const float* bias   = (const float*)d_in[3];
    float*       out    = (float*)d_out;

    if (ws_size >= WS_FULL) {
        char* w = (char*)d_ws;
        unsigned short* Wt  = (unsigned short*)w;
        float*          pe  = (float*)(w + WT_BYTES);
        float*          x   = (float*)(w + WT_BYTES + PE_BYTES);
        unsigned short* Abf = (unsigned short*)(w + WT_BYTES + PE_BYTES + X_BYTES);

        prep_all<<<dim3(1024 + 256 + 4096), dim3(256), 0, stream>>>(
            tokens, emb, W, bias, Wt, pe, Abf);
        gemm_dense<<<dim3(MODELS / 64, BATCH / 64), dim3(256), 0, stream>>>(Abf, Wt, x);
        bcast_pe<<<dim3(BATCH / 2), dim3(256), 0, stream>>>(x, pe, out);
    } else if (ws_size >= WS_MID) {
        char* w = (char*)d_ws;
        unsigned short* Wt = (unsigned short*)w;
        float* pe = (float*)(w + WT_BYTES);
        float* x  = (float*)(w + WT_BYTES + PE_BYTES);

        prep_wt<<<dim3(KDIM / 32, MODELS / 32), dim3(32, 8), 0, stream>>>(W, Wt);
        prep_pe<<<dim3(SEQ * MODELS / 256), dim3(256), 0, stream>>>(bias, pe);
        gemm_mfma<<<dim3(MODELS / 256, BATCH / 16), dim3(256), 0, stream>>>(tokens, emb, Wt, x);
        bcast_pe<<<dim3(BATCH / 2), dim3(256), 0, stream>>>(x, pe, out);
    } else {
        fused_emb_gemm_pe<<<dim3(MODELS / BN, BATCH / BM), dim3(256), 0, stream>>>(
            tokens, emb, W, bias, out);
    }
}

// Round 13
// 268.402 us; speedup vs baseline: 1.2025x; 1.0021x over previous
//
#include <hip/hip_runtime.h>
#include <math.h>

#define BATCH   4096
#define FEAT    64
#define EMB     32
#define MODELS  512
#define SEQ     128
#define KDIM    (FEAT * EMB)   // 2048

#define SQRT_MODELS 22.62741699796952f
#define LN10000     9.210340371976184f

typedef __attribute__((ext_vector_type(4))) float        f32x4;
typedef __attribute__((ext_vector_type(8))) short        bf16x8;
typedef __attribute__((ext_vector_type(4))) unsigned int u32x4;

// ws layout: Wt | pe | x | Abf
#define WT_BYTES  ((size_t)MODELS * KDIM * 2)          // 2 MB   bf16 W^T, pre-scaled
#define PE_BYTES  ((size_t)SEQ * MODELS * 4)           // 256 KB pe + bias
#define X_BYTES   ((size_t)BATCH * MODELS * 4)         // 8 MB
#define ABF_BYTES ((size_t)BATCH * KDIM * 2)           // 16 MB  dense bf16 A
#define WS_MID    (WT_BYTES + PE_BYTES + X_BYTES)
#define WS_FULL   (WT_BYTES + PE_BYTES + X_BYTES + ABF_BYTES)

__device__ inline unsigned short bf16_rne(float f) {
    unsigned int b = __builtin_bit_cast(unsigned int, f);
    return (unsigned short)((b + 0x7FFFu + ((b >> 16) & 1u)) >> 16);
}

#define CVT_PK4(pk, v0, v1)                                                     \
    {                                                                           \
        unsigned int q0, q1, q2, q3;                                            \
        asm("v_cvt_pk_bf16_f32 %0, %1, %2" : "=v"(q0) : "v"(v0.x), "v"(v0.y));  \
        asm("v_cvt_pk_bf16_f32 %0, %1, %2" : "=v"(q1) : "v"(v0.z), "v"(v0.w));  \
        asm("v_cvt_pk_bf16_f32 %0, %1, %2" : "=v"(q2) : "v"(v1.x), "v"(v1.y));  \
        asm("v_cvt_pk_bf16_f32 %0, %1, %2" : "=v"(q3) : "v"(v1.z), "v"(v1.w));  \
        pk = (u32x4){q0, q1, q2, q3};                                           \
    }

// ---------------- prep_all: Wt transpose | pe table | dense gather (proven R7) ----------------
__global__ __launch_bounds__(256)
void prep_all(const int* __restrict__ tokens, const float* __restrict__ emb,
              const float* __restrict__ W, const float* __restrict__ bias,
              unsigned short* __restrict__ Wt, float* __restrict__ pe,
              unsigned short* __restrict__ Abf) {
    const int bx  = blockIdx.x;
    const int tid = threadIdx.x;

    if (bx < 1024) {
        __shared__ float t[32][33];
        const int k0 = (bx & 63) * 32;
        const int n0 = (bx >> 6) * 32;
        const int tx = tid & 31;
        const int ty = tid >> 5;
        #pragma unroll
        for (int i = 0; i < 4; ++i)
            t[ty + i * 8][tx] = W[(size_t)(k0 + ty + i * 8) * MODELS + n0 + tx] * SQRT_MODELS;
        __syncthreads();
        #pragma unroll
        for (int i = 0; i < 4; ++i)
            Wt[(size_t)(n0 + ty + i * 8) * KDIM + k0 + tx] = bf16_rne(t[tx][ty + i * 8]);
    } else if (bx < 1280) {
        const int idx = (bx - 1024) * 256 + tid;
        const int s = idx >> 9;
        const int m = idx & (MODELS - 1);
        const float rate = expf(-LN10000 * (float)(2 * (m >> 1)) * (1.0f / 512.0f));
        const float ang  = (float)s * rate;
        pe[idx] = ((m & 1) ? cosf(ang) : sinf(ang)) + bias[m];
    } else {
        const int g    = (bx - 1280) * 256 + tid;     // 0 .. 1M-1
        const int fr   = g >> 2;
        const int part = g & 3;
        const int tok  = tokens[fr];
        const float* src = emb + (size_t)tok * EMB + part * 8;
        const f32x4 v0 = *(const f32x4*)src;
        const f32x4 v1 = *(const f32x4*)(src + 4);
        u32x4 pk;
        CVT_PK4(pk, v0, v1);
        *(u32x4*)(Abf + (size_t)g * 8) = pk;
    }
}

// ---------------- GEMM: x = Abf @ Wt^T  (R12-verified; grid transposed for XCD L2 reuse) ----------------
// grid (BATCH/64, MODELS/64) = (64, 8): linear id = bx + 64*by -> XCD = bx % 8, so all
// 8 n-tile blocks of one m-tile share an XCD; its 2 MB Abf slice is L2-resident (+2 MB Wt = 4 MB L2).
__global__ __launch_bounds__(256)
void gemm_dense(const unsigned short* __restrict__ Abf,
                const unsigned short* __restrict__ Wt,
                float* __restrict__ x) {
    const int tid  = threadIdx.x;
    const int lane = tid & 63;
    const int wave = tid >> 6;
    const int ln   = lane & 15;
    const int kg   = lane >> 4;
    const int m0 = blockIdx.x * 64 + (wave >> 1) * 32;   // m-tile on x (XCD-major)
    const int n0 = blockIdx.y * 64 + (wave & 1) * 32;    // n-tile on y

    const unsigned short* a0p = Abf + (size_t)(m0 + ln) * KDIM + kg * 8;
    const unsigned short* a1p = a0p + 16 * KDIM;
    const unsigned short* b0p = Wt + (size_t)(n0 + ln) * KDIM + kg * 8;
    const unsigned short* b1p = b0p + 16 * KDIM;

    f32x4 acc00 = {0,0,0,0}, acc01 = {0,0,0,0};
    f32x4 acc10 = {0,0,0,0}, acc11 = {0,0,0,0};

    #pragma unroll 8
    for (int k = 0; k < KDIM; k += 32) {
        const bf16x8 a0 = *(const bf16x8*)(a0p + k);
        const bf16x8 a1 = *(const bf16x8*)(a1p + k);
        const bf16x8 b0 = *(const bf16x8*)(b0p + k);
        const bf16x8 b1 = *(const bf16x8*)(b1p + k);
        acc00 = __builtin_amdgcn_mfma_f32_16x16x32_bf16(a0, b0, acc00, 0, 0, 0);
        acc01 = __builtin_amdgcn_mfma_f32_16x16x32_bf16(a0, b1, acc01, 0, 0, 0);
        acc10 = __builtin_amdgcn_mfma_f32_16x16x32_bf16(a1, b0, acc10, 0, 0, 0);
        acc11 = __builtin_amdgcn_mfma_f32_16x16x32_bf16(a1, b1, acc11, 0, 0, 0);
    }
    // D mapping (verified): col = lane&15, row = (lane>>4)*4 + reg
    #pragma unroll
    for (int q = 0; q < 4; ++q) {
        const int r = kg * 4 + q;
        x[(size_t)(m0 + r)      * MODELS + n0 + ln]      = acc00[q];
        x[(size_t)(m0 + r)      * MODELS + n0 + 16 + ln] = acc01[q];
        x[(size_t)(m0 + 16 + r) * MODELS + n0 + ln]      = acc10[q];
        x[(size_t)(m0 + 16 + r) * MODELS + n0 + 16 + ln] = acc11[q];
    }
}

// ---------------- bcast: out[b][s][m] = x[b][m] + pe[s][m], NT stores (proven R12) ----------------
__global__ __launch_bounds__(256)
void bcast_pe(const float* __restrict__ x, const float* __restrict__ pe,
              float* __restrict__ out) {
    const int tid = threadIdx.x;
    const int m4  = tid & 127;
    const int b   = blockIdx.x * 2 + (tid >> 7);
    const f32x4 xv = *(const f32x4*)(x + (size_t)b * MODELS + m4 * 4);
    const f32x4* pev = (const f32x4*)pe;
    float* ob = out + (size_t)b * SEQ * MODELS + m4 * 4;
    #pragma unroll 16
    for (int s = 0; s < SEQ; ++s) {
        const f32x4 p = pev[s * 128 + m4];
        __builtin_nontemporal_store(xv + p, (f32x4*)(ob + (size_t)s * MODELS));
    }
}

// ---------------- mid-path (proven R2): gather-direct MFMA + separate bcast ----------------
__global__ __launch_bounds__(256)
void gemm_mfma(const int* __restrict__ tokens, const float* __restrict__ emb,
               const unsigned short* __restrict__ Wt, float* __restrict__ x) {
    const int tid  = threadIdx.x;
    const int wave = tid >> 6;
    const int lane = tid & 63;
    const int ln   = lane & 15;
    const int kg   = lane >> 4;
    const int m_base = blockIdx.y * 16;
    const int n_base = blockIdx.x * 256 + wave * 64;
    const int* trow = tokens + (size_t)(m_base + ln) * FEAT;
    const unsigned short* bptr[4];
    #pragma unroll
    for (int nf = 0; nf < 4; ++nf)
        bptr[nf] = Wt + (size_t)(n_base + nf * 16 + ln) * KDIM + kg * 8;
    f32x4 acc[4] = {f32x4{0,0,0,0}, f32x4{0,0,0,0}, f32x4{0,0,0,0}, f32x4{0,0,0,0}};
    for (int f4 = 0; f4 < FEAT; f4 += 4) {
        const int4 tok4 = *(const int4*)(trow + f4);
        const int toks[4] = {tok4.x, tok4.y, tok4.z, tok4.w};
        #pragma unroll
        for (int j = 0; j < 4; ++j) {
            const int f = f4 + j;
            const float* ea = emb + (size_t)toks[j] * EMB + kg * 8;
            const f32x4 a0 = *(const f32x4*)ea;
            const f32x4 a1 = *(const f32x4*)(ea + 4);
            u32x4 pk;
            CVT_PK4(pk, a0, a1);
            const bf16x8 afrag = __builtin_bit_cast(bf16x8, pk);
            #pragma unroll
            for (int nf = 0; nf < 4; ++nf) {
                const bf16x8 bfrag = *(const bf16x8*)(bptr[nf] + (size_t)f * EMB);
                acc[nf] = __builtin_amdgcn_mfma_f32_16x16x32_bf16(afrag, bfrag, acc[nf], 0, 0, 0);
            }
        }
    }
    #pragma unroll
    for (int nf = 0; nf < 4; ++nf)
        #pragma unroll
        for (int q = 0; q < 4; ++q)
            x[(size_t)(m_base + kg * 4 + q) * MODELS + n_base + nf * 16 + ln] = acc[nf][q];
}

__global__ __launch_bounds__(256)
void prep_wt(const float* __restrict__ W, unsigned short* __restrict__ Wt) {
    __shared__ float t[32][33];
    const int k0 = blockIdx.x * 32;
    const int n0 = blockIdx.y * 32;
    const int tx = threadIdx.x;
    const int ty = threadIdx.y;
    #pragma unroll
    for (int i = 0; i < 4; ++i)
        t[ty + i * 8][tx] = W[(size_t)(k0 + ty + i * 8) * MODELS + n0 + tx] * SQRT_MODELS;
    __syncthreads();
    #pragma unroll
    for (int i = 0; i < 4; ++i)
        Wt[(size_t)(n0 + ty + i * 8) * KDIM + k0 + tx] = bf16_rne(t[tx][ty + i * 8]);
}

__global__ __launch_bounds__(256)
void prep_pe(const float* __restrict__ bias, float* __restrict__ pe) {
    const int idx = blockIdx.x * 256 + threadIdx.x;
    const int s = idx >> 9;
    const int m = idx & (MODELS - 1);
    const float rate = expf(-LN10000 * (float)(2 * (m >> 1)) * (1.0f / 512.0f));
    const float ang  = (float)s * rate;
    pe[idx] = ((m & 1) ? cosf(ang) : sinf(ang)) + bias[m];
}

// ---------------- last-resort fallback: verified round-1 fused kernel ----------------
#define BM 64
#define BN 64
#define BK 32
__global__ __launch_bounds__(256, 2)
void fused_emb_gemm_pe(const int* __restrict__ tokens, const float* __restrict__ emb,
                       const float* __restrict__ W, const float* __restrict__ bias,
                       float* __restrict__ out) {
    __shared__ float As[BK][BM];
    __shared__ float Bs[BK][BN];
    __shared__ float peS[SEQ][BN];
    const int tid  = threadIdx.x;
    const int bn   = blockIdx.x * BN;
    const int brow = blockIdx.y * BM;
    for (int idx = tid; idx < SEQ * BN; idx += 256) {
        const int s  = idx >> 6;
        const int ml = idx & 63;
        const int m  = bn + ml;
        const float rate = expf(-LN10000 * (float)(2 * (m >> 1)) * (1.0f / 512.0f));
        const float ang  = (float)s * rate;
        peS[s][ml] = (m & 1) ? cosf(ang) : sinf(ang);
    }
    float acc[4][4] = {};
    const int tx = tid & 15;
    const int ty = tid >> 4;
    const int lr = tid >> 2;
    const int lj = tid & 3;
    const int bk = tid >> 4;
    const int bc = (tid & 15) * 4;
    for (int kt = 0; kt < FEAT; ++kt) {
        __syncthreads();
        {
            const int tok = tokens[(brow + lr) * FEAT + kt];
            const float* erow = emb + (size_t)tok * EMB + lj * 8;
            const float4 a0 = *(const float4*)(erow);
            const float4 a1 = *(const float4*)(erow + 4);
            const int k0 = lj * 8;
            As[k0 + 0][lr] = a0.x * SQRT_MODELS; As[k0 + 1][lr] = a0.y * SQRT_MODELS;
            As[k0 + 2][lr] = a0.z * SQRT_MODELS; As[k0 + 3][lr] = a0.w * SQRT_MODELS;
            As[k0 + 4][lr] = a1.x * SQRT_MODELS; As[k0 + 5][lr] = a1.y * SQRT_MODELS;
            As[k0 + 6][lr] = a1.z * SQRT_MODELS; As[k0 + 7][lr] = a1.w * SQRT_MODELS;
        }
        {
            const float* w0 = W + (size_t)(kt * 32 + bk) * MODELS + bn + bc;
            const float* w1 = W + (size_t)(kt * 32 + bk + 16) * MODELS + bn + bc;
            *(float4*)&Bs[bk][bc]      = *(const float4*)w0;
            *(float4*)&Bs[bk + 16][bc] = *(const float4*)w1;
        }
        __syncthreads();
        #pragma unroll
        for (int k = 0; k < BK; ++k) {
            const float4 a = *(const float4*)&As[k][ty * 4];
            const float4 b = *(const float4*)&Bs[k][tx * 4];
            acc[0][0] += a.x * b.x; acc[0][1] += a.x * b.y; acc[0][2] += a.x * b.z; acc[0][3] += a.x * b.w;
            acc[1][0] += a.y * b.x; acc[1][1] += a.y * b.y; acc[1][2] += a.y * b.z; acc[1][3] += a.y * b.w;
            acc[2][0] += a.z * b.x; acc[2][1] += a.z * b.y; acc[2][2] += a.z * b.z; acc[2][3] += a.z * b.w;
            acc[3][0] += a.w * b.x; acc[3][1] += a.w * b.y; acc[3][2] += a.w * b.z; acc[3][3] += a.w * b.w;
        }
    }
    {
        const float4 bv = *(const float4*)(bias + bn + tx * 4);
        #pragma unroll
        for (int i = 0; i < 4; ++i) {
            acc[i][0] += bv.x; acc[i][1] += bv.y; acc[i][2] += bv.z; acc[i][3] += bv.w;
        }
    }
    size_t rowbase[4];
    #pragma unroll
    for (int i = 0; i < 4; ++i)
        rowbase[i] = ((size_t)(brow + ty * 4 + i) * SEQ) * MODELS + bn + tx * 4;
    #pragma unroll 4
    for (int s = 0; s < SEQ; ++s) {
        const float4 pv = *(const float4*)&peS[s][tx * 4];
        const size_t soff = (size_t)s * MODELS;
        #pragma unroll
        for (int i = 0; i < 4; ++i) {
            float4 o;
            o.x = acc[i][0] + pv.x; o.y = acc[i][1] + pv.y;
            o.z = acc[i][2] + pv.z; o.w = acc[i][3] + pv.w;
            *(float4*)(out + rowbase[i] + soff) = o;
        }
    }
}

extern "C" void kernel_launch(void* const* d_in, const int* in_sizes, int n_in,
                              void* d_out, int out_size, void* d_ws, size_t ws_size,
                              hipStream_t stream) {
    const int*   tokens = (const int*)d_in[0];
    const float* emb    = (const float*)d_in[1];
    const float* W      = (const float*)d_in[2];
    const float* bias   = (const float*)d_in[3];
    float*       out    = (float*)d_out;

    if (ws_size >= WS_FULL) {
        char* w = (char*)d_ws;
        unsigned short* Wt  = (unsigned short*)w;
        float*          pe  = (float*)(w + WT_BYTES);
        float*          x   = (float*)(w + WT_BYTES + PE_BYTES);
        unsigned short* Abf = (unsigned short*)(w + WT_BYTES + PE_BYTES + X_BYTES);

        prep_all<<<dim3(1024 + 256 + 4096), dim3(256), 0, stream>>>(
            tokens, emb, W, bias, Wt, pe, Abf);
        gemm_dense<<<dim3(BATCH / 64, MODELS / 64), dim3(256), 0, stream>>>(Abf, Wt, x);
        bcast_pe<<<dim3(BATCH / 2), dim3(256), 0, stream>>>(x, pe, out);
    } else if (ws_size >= WS_MID) {
        char* w = (char*)d_ws;
        unsigned short* Wt = (unsigned short*)w;
        float* pe = (float*)(w + WT_BYTES);
        float* x  = (float*)(w + WT_BYTES + PE_BYTES);

        prep_wt<<<dim3(KDIM / 32, MODELS / 32), dim3(32, 8), 0, stream>>>(W, Wt);
        prep_pe<<<dim3(SEQ * MODELS / 256), dim3(256), 0, stream>>>(bias, pe);
        gemm_mfma<<<dim3(MODELS / 256, BATCH / 16), dim3(256), 0, stream>>>(tokens, emb, Wt, x);
        bcast_pe<<<dim3(BATCH / 2), dim3(256), 0, stream>>>(x, pe, out);
    } else {
        fused_emb_gemm_pe<<<dim3(MODELS / BN, BATCH / BM), dim3(256), 0, stream>>>(
            tokens, emb, W, bias, out);
    }
}